// Round 6
// baseline (108.430 us; speedup 1.0000x reference)
//
#include <hip/hip_runtime.h>

#define NPTS 8192      // H*W
#define BCLS 4         // C
#define NP   6         // B*(C-1) pairs
#define R2   9.0f
#define RAD  3.0f
#define GRD  64
#define NCELL (GRD*GRD)
#define PCAP 2048      // pending-list capacity (overflow -> sweep fallback in k_rounds)
#define CAP  4096      // per-pair compact-point capacity (M ~ 2048 +- 40)
#define KBLK 64        // front kernel blocks
#define KTHR 256       // front kernel threads
#define NSL  8         // slices per pair for wide kernels
#define WBLK (NP*NSL)  // 48 wide blocks
#define WTHR 256

#define ST_U 0u
#define ST_A 1u
#define ST_D 2u

// ---------------------------------------------------------------------------
// R19: full phase fission. R18 attributed ~52us to the 6-block engine; block-
// level counters can't split it further. Fission by intrinsic parallelism:
//   k_front  (64x256)  argmax+compact slabs+zero out/ksum     [R18 verbatim]
//   k_build  ( 6x1024) gather->bbox->grid scatter, dump state to global
//   k_sweep  (48x256)  WIDE round-0: decide/append pending (global state;
//                      stale-U reads conservative; statuses monotone)
//   k_rounds ( 6x1024) pending rounds to fixpoint in LDS (R11 engine
//                      verbatim) + kept-rank table -> global
//   k_assign (48x256)  WIDE argmin-to-kept + global f32 atomic accumulate
//   k_out    (48x256)  WIDE kept writes: out = sum/cnt, ok = 1
// Cross-kernel visibility via kernel boundaries; within-kernel cross-block
// races stay inside the proven monotone-conservative framework.
// ---------------------------------------------------------------------------

__global__ __launch_bounds__(KTHR) void k_front(
    const float* __restrict__ seg, const float* __restrict__ lidar,
    float* __restrict__ xs, float* __restrict__ ys,
    unsigned int* __restrict__ ns, unsigned int* __restrict__ counts,
    unsigned int* __restrict__ pcnt_g, float* __restrict__ ksum,
    float* __restrict__ out)
{
    const int tid = threadIdx.x, lane = tid & 63;
    const int idx = blockIdx.x * KTHR + tid;       // [0, B*NPTS)
    const int b = idx >> 13, n = idx & 8191;

    __shared__ float ex[KTHR], ey[KTHR];
    __shared__ unsigned short en[KTHR];
    __shared__ unsigned int cnt6[6], off6[6], pos6[6];

    if (tid < 6) cnt6[tid] = 0;
    __syncthreads();

    // per-pixel argmax (strict >: first index wins ties)
    const float* segb = seg + (size_t)b * BCLS * NPTS + n;
    float bv = segb[0];
    int bc = 0;
    #pragma unroll
    for (int c = 1; c < BCLS; ++c) {
        float v = segb[(size_t)c * NPTS];
        if (v > bv) { bv = v; bc = c; }
    }
    const float x = lidar[(size_t)b * 2 * NPTS + n];
    const float y = lidar[(size_t)b * 2 * NPTS + NPTS + n];
    const int p = (bc > 0) ? (b * 3 + bc - 1) : -1;

    #pragma unroll
    for (int q = 0; q < 6; ++q) {
        unsigned long long bal = __ballot(p == q);
        if (lane == 0 && bal) atomicAdd(&cnt6[q], (unsigned int)__popcll(bal));
    }
    __syncthreads();
    if (tid == 0) {
        unsigned int a = 0;
        #pragma unroll
        for (int q = 0; q < 6; ++q) { off6[q] = a; pos6[q] = a; a += cnt6[q]; }
    }
    __syncthreads();
    #pragma unroll
    for (int q = 0; q < 6; ++q) {
        unsigned long long bal = __ballot(p == q);
        if (bal) {
            int ldr = __builtin_ctzll(bal);
            unsigned int wb = 0;
            if (lane == ldr) wb = atomicAdd(&pos6[q], (unsigned int)__popcll(bal));
            wb = __shfl(wb, ldr, 64);
            if (p == q) {
                unsigned int s = wb + (unsigned int)__popcll(bal & ((1ull << lane) - 1ull));
                ex[s] = x; ey[s] = y; en[s] = (unsigned short)n;
            }
        }
    }
    __syncthreads();
    {
        const unsigned int total = off6[5] + cnt6[5];
        const int gbase = blockIdx.x * KTHR;
        for (int k = tid; k < (int)total; k += KTHR) {
            xs[gbase + k] = ex[k];
            ys[gbase + k] = ey[k];
            ns[gbase + k] = (unsigned int)en[k];
        }
        if (tid < 6) counts[blockIdx.x * 6 + tid] = cnt6[tid];
    }
    // zero out+ok (147456 f = 36864 float4) and ksum (73728 f = 18432 float4)
    {
        float4* o4 = (float4*)out;
        for (int k = idx; k < 36864; k += KBLK * KTHR)
            o4[k] = make_float4(0.f, 0.f, 0.f, 0.f);
        float4* s4 = (float4*)ksum;
        for (int k = idx; k < 18432; k += KBLK * KTHR)
            s4[k] = make_float4(0.f, 0.f, 0.f, 0.f);
        if (idx < 6) pcnt_g[idx] = 0;
    }
}

// ---------------------------------------------------------------------------
__global__ __launch_bounds__(1024) void k_build(
    const float* __restrict__ xs, const float* __restrict__ ys,
    const unsigned int* __restrict__ ns, const unsigned int* __restrict__ counts,
    float2* __restrict__ sps_g, unsigned int* __restrict__ cmb_g,
    unsigned int* __restrict__ cellpack_g, float* __restrict__ bbox_g,
    int* __restrict__ M_g)
{
    const int p = blockIdx.x;
    const int tid = threadIdx.x, lane = tid & 63, wv = tid >> 6;

    __shared__ float2 sps[CAP];                 // 32 KB
    __shared__ unsigned int cmb[CAP];           // 16 KB
    __shared__ unsigned int cellpack[NCELL];    // 16 KB
    __shared__ unsigned int csrc[KBLK], cdst[KBLK];
    __shared__ unsigned int wtot[16];
    __shared__ float redbuf[4][16];
    __shared__ float sbminx, sbminy, scell;
    __shared__ int sM;

    for (int k = tid; k < CAP; k += 1024) cmb[k] = ST_U;
    for (int k = tid; k < NCELL; k += 1024) cellpack[k] = 0u;

    if (wv == 0) {                              // chunk table over 64 source blocks
        unsigned int c6[6];
        #pragma unroll
        for (int q = 0; q < 6; ++q) c6[q] = counts[lane * 6 + q];
        unsigned int within = 0;
        for (int q = 0; q < p; ++q) within += c6[q];
        unsigned int len = c6[p];
        unsigned int v = len;
        for (int d = 1; d < 64; d <<= 1) {
            unsigned int u = __shfl_up(v, d, 64);
            if (lane >= d) v += u;
        }
        csrc[lane] = lane * KTHR + within;
        cdst[lane] = v - len;
        if (lane == 63) sM = (int)(v < CAP ? v : CAP);
    }
    __syncthreads();
    const int M = sM;

    // gather compact entries into regs + bbox
    float xq[8], yq[8];
    unsigned int nq[8];
    int liq[8];
    {
        float mnx = 3e38f, mxx = -3e38f, mny = 3e38f, mxy = -3e38f;
        #pragma unroll
        for (int q = 0; q < 8; ++q) {
            int li = q * 1024 + tid;
            liq[q] = li;
            if (li < M) {
                int lo = 0, hi = KBLK - 1;
                #pragma unroll
                for (int s = 0; s < 6; ++s) {
                    int mid = (lo + hi + 1) >> 1;
                    if (cdst[mid] <= (unsigned int)li) lo = mid; else hi = mid - 1;
                }
                int si = csrc[lo] + (li - cdst[lo]);
                float x = xs[si], y = ys[si];
                xq[q] = x; yq[q] = y; nq[q] = ns[si];
                mnx = fminf(mnx, x); mxx = fmaxf(mxx, x);
                mny = fminf(mny, y); mxy = fmaxf(mxy, y);
            }
        }
        for (int d = 32; d; d >>= 1) {
            mnx = fminf(mnx, __shfl_xor(mnx, d, 64));
            mxx = fmaxf(mxx, __shfl_xor(mxx, d, 64));
            mny = fminf(mny, __shfl_xor(mny, d, 64));
            mxy = fmaxf(mxy, __shfl_xor(mxy, d, 64));
        }
        if (lane == 0) { redbuf[0][wv] = mnx; redbuf[1][wv] = mxx;
                         redbuf[2][wv] = mny; redbuf[3][wv] = mxy; }
    }
    __syncthreads();
    if (tid == 0) {
        float a = redbuf[0][0], b2 = redbuf[1][0], c = redbuf[2][0], d = redbuf[3][0];
        for (int q = 1; q < 16; ++q) {
            a = fminf(a, redbuf[0][q]); b2 = fmaxf(b2, redbuf[1][q]);
            c = fminf(c, redbuf[2][q]); d = fmaxf(d, redbuf[3][q]);
        }
        sbminx = a; sbminy = c;
        scell = fmaxf(2.0f * RAD, fmaxf(b2 - a, d - c) / 63.0f);
    }
    __syncthreads();
    const float bminx = sbminx, bminy = sbminy, inv = 1.0f / scell;

    // grid count / scan / scatter
    int cellq[8];
    #pragma unroll
    for (int q = 0; q < 8; ++q) {
        if (liq[q] < M) {
            int ix = min(GRD - 1, max(0, (int)((xq[q] - bminx) * inv)));
            int iy = min(GRD - 1, max(0, (int)((yq[q] - bminy) * inv)));
            cellq[q] = iy * GRD + ix;
            atomicAdd(&cellpack[cellq[q]], 1u);
        } else cellq[q] = -1;
    }
    __syncthreads();
    {
        unsigned int c4[4], t4 = 0;
        #pragma unroll
        for (int q = 0; q < 4; ++q) { c4[q] = cellpack[tid * 4 + q]; t4 += c4[q]; }
        unsigned int v = t4;
        for (int d = 1; d < 64; d <<= 1) {
            unsigned int u = __shfl_up(v, d, 64);
            if (lane >= d) v += u;
        }
        if (lane == 63) wtot[wv] = v;
        __syncthreads();
        if (tid == 0) {
            unsigned int acc = 0;
            for (int q = 0; q < 16; ++q) { unsigned int t = wtot[q]; wtot[q] = acc; acc += t; }
        }
        __syncthreads();
        unsigned int excl = wtot[wv] + v - t4;
        #pragma unroll
        for (int q = 0; q < 4; ++q) { cellpack[tid * 4 + q] = excl << 16; excl += c4[q]; }
    }
    __syncthreads();
    #pragma unroll
    for (int q = 0; q < 8; ++q) {
        if (cellq[q] >= 0) {
            unsigned int old = atomicAdd(&cellpack[cellq[q]], 1u);
            unsigned int pos = (old >> 16) + (old & 0xffffu);
            sps[pos] = make_float2(xq[q], yq[q]);
            cmb[pos] = (nq[q] << 2) | ST_U;
        }
    }
    __syncthreads();

    // dump state to global
    const int pb = p * CAP;
    for (int k = tid; k < CAP; k += 1024) { sps_g[pb + k] = sps[k]; cmb_g[pb + k] = cmb[k]; }
    for (int k = tid; k < NCELL; k += 1024) cellpack_g[p * NCELL + k] = cellpack[k];
    if (tid == 0) {
        bbox_g[p * 4 + 0] = bminx; bbox_g[p * 4 + 1] = bminy;
        bbox_g[p * 4 + 2] = inv;
        M_g[p] = M;
    }
}

// ---- global-state window scan (flags) -------------------------------------
#define G_ROW_FLAGS(CP, CM, SP, CY, CX0, CX1, NI, ME, DEAD, UNDEC)                \
{                                                                                 \
    unsigned int wa = (CP)[(CY) * GRD + (CX0)];                                   \
    unsigned int wb = (CP)[(CY) * GRD + (CX1)];                                   \
    unsigned int f0 = wa >> 16, f1 = (wb >> 16) + (wb & 0xffffu);                 \
    for (unsigned int f = f0; f < f1; ++f) {                                      \
        unsigned int wf = (CM)[f];                                                \
        float2 q = (SP)[f];                                                       \
        float dx = __fsub_rn((ME).x, q.x), dy = __fsub_rn((ME).y, q.y);           \
        float d2 = __fadd_rn(__fmul_rn(dx, dx), __fmul_rn(dy, dy));               \
        bool in = (d2 < R2) & ((int)(wf >> 2) < (NI));                            \
        DEAD  |= in & ((wf & 3u) == ST_A);                                        \
        UNDEC |= in & ((wf & 3u) == ST_U);                                        \
    }                                                                             \
}
#define G_SCAN_FLAGS(CP, CM, SP, NI, ME, DEAD, UNDEC)                             \
{                                                                                 \
    int cx0 = max(0, (int)(((ME).x - RAD - bminx) * inv));                        \
    int cx1 = min(GRD - 1, (int)(((ME).x + RAD - bminx) * inv));                  \
    int cy0 = max(0, (int)(((ME).y - RAD - bminy) * inv));                        \
    int cy1 = min(GRD - 1, (int)(((ME).y + RAD - bminy) * inv));                  \
    DEAD = false; UNDEC = false;                                                  \
    G_ROW_FLAGS(CP, CM, SP, cy0, cx0, cx1, NI, ME, DEAD, UNDEC);                  \
    if (cy1 > cy0) G_ROW_FLAGS(CP, CM, SP, cy1, cx0, cx1, NI, ME, DEAD, UNDEC);   \
}

// ---------------------------------------------------------------------------
__global__ __launch_bounds__(WTHR) void k_sweep(
    const float2* __restrict__ sps_g, unsigned int* __restrict__ cmb_g,
    const unsigned int* __restrict__ cellpack_g, const float* __restrict__ bbox_g,
    const int* __restrict__ M_g, unsigned int* __restrict__ plist_g,
    unsigned int* __restrict__ pcnt_g)
{
    const int p = blockIdx.x / NSL, s = blockIdx.x % NSL;
    const int tid = threadIdx.x, lane = tid & 63;
    const int M = M_g[p];
    const float bminx = bbox_g[p * 4], bminy = bbox_g[p * 4 + 1], inv = bbox_g[p * 4 + 2];
    const float2* sp = sps_g + p * CAP;
    unsigned int* cm = cmb_g + p * CAP;
    const unsigned int* cp = cellpack_g + p * NCELL;

    const int chunk = (M + NSL - 1) / NSL;
    const int e0 = s * chunk, e1 = min(M, e0 + chunk);

    for (int e = e0 + tid; e < e1 || __any(e < e1); e += WTHR) {
        bool act = e < e1;
        bool pendf = false;
        unsigned int w = 0;
        if (act) {
            w = cm[e];
            int ni = (int)(w >> 2);
            float2 me = sp[e];
            bool dead, undec;
            G_SCAN_FLAGS(cp, cm, sp, ni, me, dead, undec);
            if (dead) cm[e] = (w & ~3u) | ST_D;
            else if (!undec) cm[e] = (w & ~3u) | ST_A;
            pendf = !dead && undec;
        }
        unsigned long long bal = __ballot(pendf);
        int cnt = __popcll(bal);
        int wbase = 0;
        if (cnt) {
            int ldr = __builtin_ctzll(bal);
            if (lane == ldr) wbase = (int)atomicAdd(&pcnt_g[p], (unsigned int)cnt);
            wbase = __shfl(wbase, ldr, 64);
            if (pendf) {
                int pos = wbase + __popcll(bal & ((1ull << lane) - 1ull));
                if (pos < PCAP) plist_g[p * PCAP + pos] = (unsigned int)e;
            }
        }
    }
}

// ---------------------------------------------------------------------------
__global__ __launch_bounds__(1024) void k_rounds(
    const float2* __restrict__ sps_g, unsigned int* __restrict__ cmb_g,
    const unsigned int* __restrict__ cellpack_g, const float* __restrict__ bbox_g,
    const int* __restrict__ M_g, const unsigned int* __restrict__ plist_g,
    const unsigned int* __restrict__ pcnt_g,
    unsigned long long* __restrict__ ballots_g, unsigned int* __restrict__ base_g,
    int* __restrict__ sK_g)
{
    const int p = blockIdx.x;
    const int tid = threadIdx.x, lane = tid & 63, wv = tid >> 6;

    __shared__ float2 sps[CAP];                 // 32 KB
    __shared__ unsigned int cmb[CAP];           // 16 KB
    __shared__ unsigned int cellpack[NCELL];    // 16 KB
    __shared__ unsigned short plist[2][PCAP];   //  8 KB
    __shared__ unsigned long long ballots[64];
    __shared__ unsigned int base64[64];
    __shared__ int pcnt[2];

    const int M = M_g[p];
    const float bminx = bbox_g[p * 4], bminy = bbox_g[p * 4 + 1], inv = bbox_g[p * 4 + 2];
    const int pb = p * CAP;

    for (int k = tid; k < CAP; k += 1024) { sps[k] = sps_g[pb + k]; cmb[k] = cmb_g[pb + k]; }
    for (int k = tid; k < NCELL; k += 1024) cellpack[k] = cellpack_g[p * NCELL + k];
    const int pc0 = (int)pcnt_g[p];
    if (tid == 0) { pcnt[0] = pc0 > PCAP ? 0 : pc0; pcnt[1] = 0; }
    for (int k = tid; k < min(pc0, PCAP); k += 1024)
        plist[0][k] = (unsigned short)plist_g[p * PCAP + k];
    __syncthreads();

    #define ROW_FLAGS(CY, CX0, CX1, NI, ME, DEAD, UNDEC)                          \
    {                                                                             \
        unsigned int wa = cellpack[(CY) * GRD + (CX0)];                           \
        unsigned int wb = cellpack[(CY) * GRD + (CX1)];                           \
        unsigned int f0 = wa >> 16, f1 = (wb >> 16) + (wb & 0xffffu);             \
        for (unsigned int f = f0; f < f1; ++f) {                                  \
            unsigned int wf = cmb[f];                                             \
            float2 q = sps[f];                                                    \
            float dx = __fsub_rn((ME).x, q.x), dy = __fsub_rn((ME).y, q.y);       \
            float d2 = __fadd_rn(__fmul_rn(dx, dx), __fmul_rn(dy, dy));           \
            bool in = (d2 < R2) & ((int)(wf >> 2) < (NI));                        \
            DEAD  |= in & ((wf & 3u) == ST_A);                                    \
            UNDEC |= in & ((wf & 3u) == ST_U);                                    \
        }                                                                         \
    }
    #define SCAN_FLAGS(NI, ME, DEAD, UNDEC)                                       \
    {                                                                             \
        int cx0 = max(0, (int)(((ME).x - RAD - bminx) * inv));                    \
        int cx1 = min(GRD - 1, (int)(((ME).x + RAD - bminx) * inv));              \
        int cy0 = max(0, (int)(((ME).y - RAD - bminy) * inv));                    \
        int cy1 = min(GRD - 1, (int)(((ME).y + RAD - bminy) * inv));              \
        DEAD = false; UNDEC = false;                                              \
        ROW_FLAGS(cy0, cx0, cx1, NI, ME, DEAD, UNDEC);                            \
        if (cy1 > cy0) ROW_FLAGS(cy1, cx0, cx1, NI, ME, DEAD, UNDEC);             \
    }

    if (pc0 > PCAP) {
        // overflow fallback: full sweeps to fixpoint
        for (;;) {
            bool any = false;
            __syncthreads();
            for (int e = tid; e < M; e += 1024) {
                unsigned int w = cmb[e];
                if ((w & 3u) != ST_U) continue;
                int ni = (int)(w >> 2);
                float2 me = sps[e];
                bool dead, undec;
                SCAN_FLAGS(ni, me, dead, undec);
                if (dead) cmb[e] = (w & ~3u) | ST_D;
                else if (!undec) cmb[e] = (w & ~3u) | ST_A;
                else any = true;
            }
            if (__syncthreads_count(any) == 0) break;
        }
    } else {
        // proven R11 two-buffer round engine
        int cur = 0;
        for (int round = 0; round < NPTS; ++round) {
            __syncthreads();
            int pc = pcnt[cur];
            if (pc == 0) break;
            if (tid == 0) pcnt[cur ^ 1] = 0;
            __syncthreads();
            for (int idx = tid; idx < pc; idx += 1024) {
                int e = plist[cur][idx];
                unsigned int w = cmb[e];
                int ni = (int)(w >> 2);
                float2 me = sps[e];
                bool dead, undec;
                SCAN_FLAGS(ni, me, dead, undec);
                if (dead) cmb[e] = (w & ~3u) | ST_D;
                else if (!undec) cmb[e] = (w & ~3u) | ST_A;
                bool pendf = !dead && undec;
                unsigned long long act = __ballot(true);
                unsigned long long bal = __ballot(pendf);
                int leader = __builtin_ctzll(act);
                int cnt = __popcll(bal);
                int wbase = 0;
                if (lane == leader && cnt) wbase = atomicAdd(&pcnt[cur ^ 1], cnt);
                wbase = __shfl(wbase, leader, 64);
                if (pendf) {
                    int pos = wbase + __popcll(bal & ((1ull << lane) - 1ull));
                    if (pos < PCAP) plist[cur ^ 1][pos] = (unsigned short)e;
                }
            }
            cur ^= 1;
        }
    }
    __syncthreads();

    // kept-rank table: 64 words over CAP=4096 entries
    for (int k = 0; k < 4; ++k) {
        int e = (k << 10) + tid;
        unsigned long long bal = __ballot((cmb[e] & 3u) == ST_A);  // e>=M stays U
        if (lane == 0) ballots[(k << 4) + wv] = bal;
    }
    __syncthreads();
    if (wv == 0) {
        unsigned int s = (unsigned int)__popcll(ballots[lane]);
        unsigned int v = s;
        for (int d = 1; d < 64; d <<= 1) {
            unsigned int u = __shfl_up(v, d, 64);
            if (lane >= d) v += u;
        }
        base64[lane] = v - s;
        if (lane == 63) sK_g[p] = (int)v;
    }
    __syncthreads();

    // write back statuses + rank table
    for (int k = tid; k < CAP; k += 1024) cmb_g[pb + k] = cmb[k];
    if (tid < 64) { ballots_g[(p << 6) + tid] = ballots[tid]; base_g[(p << 6) + tid] = base64[tid]; }
}

#define KRANK_G(P, E) ((int)base_g[((P) << 6) + ((E) >> 6)] +                     \
    __popcll(ballots_g[((P) << 6) + ((E) >> 6)] & ((1ull << ((E) & 63)) - 1ull)))

// ---------------------------------------------------------------------------
__global__ __launch_bounds__(WTHR) void k_assign(
    const float2* __restrict__ sps_g, const unsigned int* __restrict__ cmb_g,
    const unsigned int* __restrict__ cellpack_g, const float* __restrict__ bbox_g,
    const int* __restrict__ M_g,
    const unsigned long long* __restrict__ ballots_g, const unsigned int* __restrict__ base_g,
    float* __restrict__ ksx, float* __restrict__ ksy, float* __restrict__ kcn)
{
    const int p = blockIdx.x / NSL, s = blockIdx.x % NSL;
    const int tid = threadIdx.x;
    const int M = M_g[p];
    const float bminx = bbox_g[p * 4], bminy = bbox_g[p * 4 + 1], inv = bbox_g[p * 4 + 2];
    const float2* sp = sps_g + p * CAP;
    const unsigned int* cm = cmb_g + p * CAP;
    const unsigned int* cp = cellpack_g + p * NCELL;

    const int chunk = (M + NSL - 1) / NSL;
    const int e0 = s * chunk, e1 = min(M, e0 + chunk);

    #define G_ROW_ARGMIN(CY, CX0, CX1, ME, BD, BE, BN)                            \
    {                                                                             \
        unsigned int wa = cp[(CY) * GRD + (CX0)];                                 \
        unsigned int wb = cp[(CY) * GRD + (CX1)];                                 \
        unsigned int f0 = wa >> 16, f1 = (wb >> 16) + (wb & 0xffffu);             \
        for (unsigned int f = f0; f < f1; ++f) {                                  \
            unsigned int wf = cm[f];                                              \
            float2 q = sp[f];                                                     \
            float dx = __fsub_rn((ME).x, q.x), dy = __fsub_rn((ME).y, q.y);       \
            float d2 = __fadd_rn(__fmul_rn(dx, dx), __fmul_rn(dy, dy));           \
            int nf = (int)(wf >> 2);                                              \
            bool better = ((wf & 3u) == ST_A) &                                   \
                          ((d2 < BD) | ((d2 == BD) & (nf < BN)));                 \
            BD = better ? d2 : BD;                                                \
            BE = better ? (int)f : BE;                                            \
            BN = better ? nf : BN;                                                \
        }                                                                         \
    }
    for (int e = e0 + tid; e < e1; e += WTHR) {
        unsigned int w = cm[e];
        float2 me = sp[e];
        int be;
        if ((w & 3u) == ST_A) {
            be = e;                              // self: unique d2 = 0
        } else {
            int cx0 = max(0, (int)((me.x - RAD - bminx) * inv));
            int cx1 = min(GRD - 1, (int)((me.x + RAD - bminx) * inv));
            int cy0 = max(0, (int)((me.y - RAD - bminy) * inv));
            int cy1 = min(GRD - 1, (int)((me.y + RAD - bminy) * inv));
            float bd = 3e38f;
            be = -1;
            int bn = 1 << 30;
            G_ROW_ARGMIN(cy0, cx0, cx1, me, bd, be, bn);
            if (cy1 > cy0) G_ROW_ARGMIN(cy1, cx0, cx1, me, bd, be, bn);
            if (be < 0) continue;
        }
        int r = KRANK_G(p, be);
        atomicAdd(&ksx[p * CAP + r], me.x);
        atomicAdd(&ksy[p * CAP + r], me.y);
        atomicAdd(&kcn[p * CAP + r], 1.0f);
    }
}

// ---------------------------------------------------------------------------
__global__ __launch_bounds__(WTHR) void k_out(
    const unsigned int* __restrict__ cmb_g, const int* __restrict__ M_g,
    const unsigned long long* __restrict__ ballots_g, const unsigned int* __restrict__ base_g,
    const float* __restrict__ ksx, const float* __restrict__ ksy,
    const float* __restrict__ kcn, float* __restrict__ out)
{
    const int p = blockIdx.x / NSL, s = blockIdx.x % NSL;
    const int tid = threadIdx.x;
    const int M = M_g[p];
    const unsigned int* cm = cmb_g + p * CAP;
    const int base = p * NPTS;
    float* ok = out + (size_t)2 * NP * NPTS + base;

    const int chunk = (M + NSL - 1) / NSL;
    const int e0 = s * chunk, e1 = min(M, e0 + chunk);

    for (int e = e0 + tid; e < e1; e += WTHR) {
        unsigned int w = cm[e];
        if ((w & 3u) != ST_A) continue;
        int n = (int)(w >> 2);
        int r = KRANK_G(p, e);
        float c = kcn[p * CAP + r];
        out[2 * (base + n)]     = ksx[p * CAP + r] / c;   // c >= 1 (self-assign)
        out[2 * (base + n) + 1] = ksy[p * CAP + r] / c;
        ok[n] = 1.0f;
    }
}

// ---------------------------------------------------------------------------
extern "C" void kernel_launch(void* const* d_in, const int* in_sizes, int n_in,
                              void* d_out, int out_size, void* d_ws, size_t ws_size,
                              hipStream_t stream) {
    const float* seg   = (const float*)d_in[0];   // [B,C,H,W] f32
    const float* lidar = (const float*)d_in[1];   // [B,2,H,W] f32
    float* out = (float*)d_out;
    float* wsf = (float*)d_ws;

    float* xs = wsf;                                        // 16384
    float* ys = wsf + 16384;                                // 16384
    unsigned int* ns = (unsigned int*)(wsf + 32768);        // 16384
    unsigned int* counts = (unsigned int*)(wsf + 49152);    // 384
    float2* sps_g = (float2*)(wsf + 49536);                 // 6*4096 float2
    unsigned int* cmb_g = (unsigned int*)(wsf + 98688);     // 6*4096
    unsigned int* cellpack_g = (unsigned int*)(wsf + 123264); // 6*4096
    unsigned int* plist_g = (unsigned int*)(wsf + 147840);  // 6*2048
    unsigned int* pcnt_g = (unsigned int*)(wsf + 160128);   // 6
    int* M_g = (int*)(wsf + 160134);                        // 6
    float* bbox_g = wsf + 160140;                           // 24
    unsigned long long* ballots_g = (unsigned long long*)(wsf + 160164); // 384 u64
    unsigned int* base_g = (unsigned int*)(wsf + 161700);   // 384
    int* sK_g = (int*)(wsf + 162084);                       // 6 (+2 pad)
    float* ksx = wsf + 162092;                              // 6*4096
    float* ksy = wsf + 186668;                              // 6*4096
    float* kcn = wsf + 211244;                              // 6*4096

    k_front <<<KBLK, KTHR, 0, stream>>>(seg, lidar, xs, ys, ns, counts, pcnt_g, ksx, out);
    k_build <<<NP, 1024, 0, stream>>>(xs, ys, ns, counts, sps_g, cmb_g, cellpack_g, bbox_g, M_g);
    k_sweep <<<WBLK, WTHR, 0, stream>>>(sps_g, cmb_g, cellpack_g, bbox_g, M_g, plist_g, pcnt_g);
    k_rounds<<<NP, 1024, 0, stream>>>(sps_g, cmb_g, cellpack_g, bbox_g, M_g, plist_g, pcnt_g,
                                      ballots_g, base_g, sK_g);
    k_assign<<<WBLK, WTHR, 0, stream>>>(sps_g, cmb_g, cellpack_g, bbox_g, M_g,
                                        ballots_g, base_g, ksx, ksy, kcn);
    k_out   <<<WBLK, WTHR, 0, stream>>>(cmb_g, M_g, ballots_g, base_g, ksx, ksy, kcn, out);
}

// Round 8
// 101.741 us; speedup vs baseline: 1.0657x; 1.0657x over previous
//
#include <hip/hip_runtime.h>

#define NPTS 8192      // H*W
#define BCLS 4         // C
#define NP   6         // B*(C-1) pairs
#define R2   9.0f
#define RAD  3.0f
#define GRD  128       // R20: fine grid — cell = max(6, span/127) ~= 2*RAD
#define NCELL (GRD*GRD)
#define PCAP 2048      // pending-list capacity (overflow -> sweep fallback)
#define LDSK 2048      // LDS kept-center accumulator cap (multi-pass if exceeded)
#define CAP  4096      // per-pair compact-point capacity (M ~ 2048 +- 40)
#define KBLK 64        // front kernel blocks
#define KTHR 256       // front kernel threads (KBLK*KTHR == B*NPTS)

#define ST_U 0u
#define ST_A 1u
#define ST_D 2u

// ---------------------------------------------------------------------------
// R21 = R20 resubmission (bench infra failed: "container failed twice"; no
// timing/counters returned, kernel unimplicated; re-audited LDS=145.6KB,
// scan coverage, ballot indices, loop termination — all sound).
// R20 rationale: R19's fission exposed the harness workspace re-poison fill
// (~40us/iter at 84% HBM peak) as the fixed ~50us floor -> only kernel sum is
// controllable. R14-R17 ruled out round machinery and scan issue latency; the
// untouched term is SCAN VOLUME: GRD=64 gives cell ~ 12.7 (2x the 2x2-window
// invariant's need), ~30 candidates/window at the Gaussian center. GRD=128 ->
// cell = max(2*RAD, span/127) ~ 6: window area /4.5 => ~4x fewer candidate
// checks in round-0, pending rescans, and P5 argmin. Semantics identical
// (cell >= 2*RAD invariant intact; same _rn arithmetic, same pixel-index
// tie-breaks; within-cell order stays arbitrary as in R11/R18).
// ---------------------------------------------------------------------------

__global__ __launch_bounds__(KTHR) void k_front(
    const float* __restrict__ seg, const float* __restrict__ lidar,
    float* __restrict__ xs, float* __restrict__ ys,
    unsigned int* __restrict__ ns, unsigned int* __restrict__ counts,
    float* __restrict__ out)
{
    const int tid = threadIdx.x, lane = tid & 63;
    const int idx = blockIdx.x * KTHR + tid;       // [0, B*NPTS)
    const int b = idx >> 13, n = idx & 8191;

    __shared__ float ex[KTHR], ey[KTHR];
    __shared__ unsigned short en[KTHR];
    __shared__ unsigned int cnt6[6], off6[6], pos6[6];

    if (tid < 6) cnt6[tid] = 0;
    __syncthreads();

    // per-pixel argmax (strict >: first index wins ties)
    const float* segb = seg + (size_t)b * BCLS * NPTS + n;
    float bv = segb[0];
    int bc = 0;
    #pragma unroll
    for (int c = 1; c < BCLS; ++c) {
        float v = segb[(size_t)c * NPTS];
        if (v > bv) { bv = v; bc = c; }
    }
    const float x = lidar[(size_t)b * 2 * NPTS + n];
    const float y = lidar[(size_t)b * 2 * NPTS + NPTS + n];
    const int p = (bc > 0) ? (b * 3 + bc - 1) : -1;

    // phase A: wave-aggregated per-pair counts
    #pragma unroll
    for (int q = 0; q < 6; ++q) {
        unsigned long long bal = __ballot(p == q);
        if (lane == 0 && bal) atomicAdd(&cnt6[q], (unsigned int)__popcll(bal));
    }
    __syncthreads();
    if (tid == 0) {
        unsigned int a = 0;
        #pragma unroll
        for (int q = 0; q < 6; ++q) { off6[q] = a; pos6[q] = a; a += cnt6[q]; }
    }
    __syncthreads();
    // phase B: wave-aggregated placement into pair-grouped staging
    #pragma unroll
    for (int q = 0; q < 6; ++q) {
        unsigned long long bal = __ballot(p == q);
        if (bal) {
            int ldr = __builtin_ctzll(bal);
            unsigned int wb = 0;
            if (lane == ldr) wb = atomicAdd(&pos6[q], (unsigned int)__popcll(bal));
            wb = __shfl(wb, ldr, 64);
            if (p == q) {
                unsigned int s = wb + (unsigned int)__popcll(bal & ((1ull << lane) - 1ull));
                ex[s] = x; ey[s] = y; en[s] = (unsigned short)n;
            }
        }
    }
    __syncthreads();
    // flush grouped staging to this block's slab chunk + counts row
    {
        const unsigned int total = off6[5] + cnt6[5];
        const int gbase = blockIdx.x * KTHR;
        for (int k = tid; k < (int)total; k += KTHR) {
            xs[gbase + k] = ex[k];
            ys[gbase + k] = ey[k];
            ns[gbase + k] = (unsigned int)en[k];
        }
        if (tid < 6) counts[blockIdx.x * 6 + tid] = cnt6[tid];
    }
    // zero out+ok: (2*NP*NPTS + NP*NPTS) floats = 147456 = 36864 float4
    {
        float4* o4 = (float4*)out;
        for (int k = idx; k < 36864; k += KBLK * KTHR)
            o4[k] = make_float4(0.f, 0.f, 0.f, 0.f);
    }
}

__global__ __launch_bounds__(1024) void k_nms(
    const float* __restrict__ xs, const float* __restrict__ ys,
    const unsigned int* __restrict__ ns, const unsigned int* __restrict__ counts,
    float* __restrict__ out)
{
    const int p = blockIdx.x;
    const int tid = threadIdx.x, lane = tid & 63, wv = tid >> 6;
    const int base = p * NPTS;

    __shared__ float2 sps[CAP];                 // 32 KB: grid-space coords
    __shared__ unsigned int cmb[CAP];           // 16 KB: pixel<<2 | status
    __shared__ unsigned int cellpack[NCELL];    // 64 KB: start<<16 | cnt
    __shared__ unsigned short plist[2][PCAP];   //  8 KB
    __shared__ float ksx[LDSK], ksy[LDSK], kcn[LDSK];  // 24 KB
    __shared__ int pcnt[2];
    __shared__ unsigned long long ballots[64];  // kept-rank words (CAP/64)
    __shared__ unsigned int base64[64];
    __shared__ unsigned int wtot[16];
    __shared__ float redbuf[4][16];
    __shared__ unsigned int csrc[KBLK], cdst[KBLK];
    __shared__ float sbminx, sbminy, scell;
    __shared__ int sM, sK;

    float* ok = out + (size_t)2 * NP * NPTS + base;

    // ---- P0: zero LDS state (out/ok zeroed by k_front) ----
    for (int k = tid; k < CAP; k += 1024) cmb[k] = ST_U;
    for (int k = tid; k < NCELL; k += 1024) cellpack[k] = 0u;
    for (int k = tid; k < LDSK; k += 1024) { ksx[k] = 0.f; ksy[k] = 0.f; kcn[k] = 0.f; }
    if (tid == 0) { pcnt[0] = 0; pcnt[1] = 0; }

    // ---- chunk table: lane k of wave 0 owns source block k ----
    if (wv == 0) {
        unsigned int c6[6];
        #pragma unroll
        for (int q = 0; q < 6; ++q) c6[q] = counts[lane * 6 + q];
        unsigned int within = 0;
        for (int q = 0; q < p; ++q) within += c6[q];
        unsigned int len = c6[p];
        unsigned int v = len;
        for (int d = 1; d < 64; d <<= 1) {
            unsigned int u = __shfl_up(v, d, 64);
            if (lane >= d) v += u;
        }
        csrc[lane] = lane * KTHR + within;
        cdst[lane] = v - len;
        if (lane == 63) sM = (int)(v < CAP ? v : CAP);
    }
    __syncthreads();
    const int M = sM;

    // ---- gather compact entries into regs + bbox (M <= CAP = 4096) ----
    float xq[4], yq[4];
    unsigned int nq[4];
    int liq[4];
    {
        float mnx = 3e38f, mxx = -3e38f, mny = 3e38f, mxy = -3e38f;
        #pragma unroll
        for (int q = 0; q < 4; ++q) {
            int li = q * 1024 + tid;
            liq[q] = li;
            if (li < M) {
                int lo = 0, hi = KBLK - 1;          // last k with cdst[k] <= li
                #pragma unroll
                for (int s = 0; s < 6; ++s) {
                    int mid = (lo + hi + 1) >> 1;
                    if (cdst[mid] <= (unsigned int)li) lo = mid; else hi = mid - 1;
                }
                int si = csrc[lo] + (li - cdst[lo]);
                float x = xs[si], y = ys[si];
                xq[q] = x; yq[q] = y; nq[q] = ns[si];
                mnx = fminf(mnx, x); mxx = fmaxf(mxx, x);
                mny = fminf(mny, y); mxy = fmaxf(mxy, y);
            }
        }
        for (int d = 32; d; d >>= 1) {
            mnx = fminf(mnx, __shfl_xor(mnx, d, 64));
            mxx = fmaxf(mxx, __shfl_xor(mxx, d, 64));
            mny = fminf(mny, __shfl_xor(mny, d, 64));
            mxy = fmaxf(mxy, __shfl_xor(mxy, d, 64));
        }
        if (lane == 0) { redbuf[0][wv] = mnx; redbuf[1][wv] = mxx;
                         redbuf[2][wv] = mny; redbuf[3][wv] = mxy; }
    }
    __syncthreads();
    if (tid == 0) {
        float a = redbuf[0][0], b2 = redbuf[1][0], c = redbuf[2][0], d = redbuf[3][0];
        for (int q = 1; q < 16; ++q) {
            a = fminf(a, redbuf[0][q]); b2 = fmaxf(b2, redbuf[1][q]);
            c = fminf(c, redbuf[2][q]); d = fmaxf(d, redbuf[3][q]);
        }
        sbminx = a; sbminy = c;
        scell = fmaxf(2.0f * RAD, fmaxf(b2 - a, d - c) / 127.0f);  // cell >= 2*RAD
    }
    __syncthreads();
    const float bminx = sbminx, bminy = sbminy, inv = 1.0f / scell;

    // ---- grid count / scan / scatter (coords held in regs) ----
    int cellq[4];
    #pragma unroll
    for (int q = 0; q < 4; ++q) {
        if (liq[q] < M) {
            int ix = min(GRD - 1, max(0, (int)((xq[q] - bminx) * inv)));
            int iy = min(GRD - 1, max(0, (int)((yq[q] - bminy) * inv)));
            cellq[q] = iy * GRD + ix;
            atomicAdd(&cellpack[cellq[q]], 1u);
        } else cellq[q] = -1;
    }
    __syncthreads();
    {
        unsigned int c16[16], t16 = 0;          // thread owns 16 cells
        #pragma unroll
        for (int q = 0; q < 16; ++q) { c16[q] = cellpack[tid * 16 + q]; t16 += c16[q]; }
        unsigned int v = t16;
        for (int d = 1; d < 64; d <<= 1) {
            unsigned int u = __shfl_up(v, d, 64);
            if (lane >= d) v += u;
        }
        if (lane == 63) wtot[wv] = v;
        __syncthreads();
        if (tid == 0) {
            unsigned int acc = 0;
            for (int q = 0; q < 16; ++q) { unsigned int t = wtot[q]; wtot[q] = acc; acc += t; }
        }
        __syncthreads();
        unsigned int excl = wtot[wv] + v - t16;
        #pragma unroll
        for (int q = 0; q < 16; ++q) { cellpack[tid * 16 + q] = excl << 16; excl += c16[q]; }
    }
    __syncthreads();
    #pragma unroll
    for (int q = 0; q < 4; ++q) {
        if (cellq[q] >= 0) {
            unsigned int old = atomicAdd(&cellpack[cellq[q]], 1u);
            unsigned int pos = (old >> 16) + (old & 0xffffu);
            sps[pos] = make_float2(xq[q], yq[q]);
            cmb[pos] = (nq[q] << 2) | ST_U;
        }
    }   // cellpack now = start<<16 | cnt; sps/cmb grid-space
    __syncthreads();

    // flat window row scan over two contiguous streams (branchless)
    #define ROW_FLAGS(CY, CX0, CX1, NI, ME, DEAD, UNDEC)                          \
    {                                                                             \
        unsigned int wa = cellpack[(CY) * GRD + (CX0)];                           \
        unsigned int wb = cellpack[(CY) * GRD + (CX1)];                           \
        unsigned int f0 = wa >> 16, f1 = (wb >> 16) + (wb & 0xffffu);             \
        for (unsigned int f = f0; f < f1; ++f) {                                  \
            unsigned int wf = cmb[f];                                             \
            float2 q = sps[f];                                                    \
            float dx = __fsub_rn((ME).x, q.x), dy = __fsub_rn((ME).y, q.y);       \
            float d2 = __fadd_rn(__fmul_rn(dx, dx), __fmul_rn(dy, dy));           \
            bool in = (d2 < R2) & ((int)(wf >> 2) < (NI));                        \
            DEAD  |= in & ((wf & 3u) == ST_A);                                    \
            UNDEC |= in & ((wf & 3u) == ST_U);                                    \
        }                                                                         \
    }
    #define SCAN_FLAGS(NI, ME, DEAD, UNDEC)                                       \
    {                                                                             \
        int cx0 = max(0, (int)(((ME).x - RAD - bminx) * inv));                    \
        int cx1 = min(GRD - 1, (int)(((ME).x + RAD - bminx) * inv));              \
        int cy0 = max(0, (int)(((ME).y - RAD - bminy) * inv));                    \
        int cy1 = min(GRD - 1, (int)(((ME).y + RAD - bminy) * inv));              \
        DEAD = false; UNDEC = false;                                              \
        ROW_FLAGS(cy0, cx0, cx1, NI, ME, DEAD, UNDEC);                            \
        if (cy1 > cy0) ROW_FLAGS(cy1, cx0, cx1, NI, ME, DEAD, UNDEC);             \
    }

    // ---- P4 round 0: full sweep (grid order), wave-ordered pending append ----
    for (int e = tid; e < M; e += 1024) {
        unsigned int w = cmb[e];
        int ni = (int)(w >> 2);
        float2 me = sps[e];
        bool dead, undec;
        SCAN_FLAGS(ni, me, dead, undec);
        if (dead) cmb[e] = (w & ~3u) | ST_D;
        else if (!undec) cmb[e] = (w & ~3u) | ST_A;
        bool pendf = !dead && undec;
        unsigned long long act = __ballot(true);
        unsigned long long bal = __ballot(pendf);
        int leader = __builtin_ctzll(act);
        int cnt = __popcll(bal);
        int wbase = 0;
        if (lane == leader && cnt) wbase = atomicAdd(&pcnt[0], cnt);
        wbase = __shfl(wbase, leader, 64);
        if (pendf) {
            int pos = wbase + __popcll(bal & ((1ull << lane) - 1ull));
            if (pos < PCAP) plist[0][pos] = (unsigned short)e;
        }
    }

    // ---- P4 rounds over compacted pending (proven engine) ----
    int cur = 0;
    for (int round = 0; round < NPTS; ++round) {
        __syncthreads();
        int pc = pcnt[cur];
        if (pc == 0) break;
        if (pc > PCAP) {                        // overflow fallback: full sweeps
            for (;;) {
                bool any = false;
                __syncthreads();
                for (int e = tid; e < M; e += 1024) {
                    unsigned int w = cmb[e];
                    if ((w & 3u) != ST_U) continue;
                    int ni = (int)(w >> 2);
                    float2 me = sps[e];
                    bool dead, undec;
                    SCAN_FLAGS(ni, me, dead, undec);
                    if (dead) cmb[e] = (w & ~3u) | ST_D;
                    else if (!undec) cmb[e] = (w & ~3u) | ST_A;
                    else any = true;
                }
                if (__syncthreads_count(any) == 0) break;
            }
            break;
        }
        if (tid == 0) pcnt[cur ^ 1] = 0;
        __syncthreads();
        for (int idx = tid; idx < pc; idx += 1024) {
            int e = plist[cur][idx];
            unsigned int w = cmb[e];
            int ni = (int)(w >> 2);
            float2 me = sps[e];
            bool dead, undec;
            SCAN_FLAGS(ni, me, dead, undec);
            if (dead) cmb[e] = (w & ~3u) | ST_D;
            else if (!undec) cmb[e] = (w & ~3u) | ST_A;
            bool pendf = !dead && undec;
            unsigned long long act = __ballot(true);
            unsigned long long bal = __ballot(pendf);
            int leader = __builtin_ctzll(act);
            int cnt = __popcll(bal);
            int wbase = 0;
            if (lane == leader && cnt) wbase = atomicAdd(&pcnt[cur ^ 1], cnt);
            wbase = __shfl(wbase, leader, 64);
            if (pendf) {
                int pos = wbase + __popcll(bal & ((1ull << lane) - 1ull));
                if (pos < PCAP) plist[cur ^ 1][pos] = (unsigned short)e;
            }
        }
        cur ^= 1;
    }
    __syncthreads();

    // ---- kept-rank over grid space: ballot bitmask + wave-scanned prefix ----
    for (int k = 0; k < 4; ++k) {
        int e = (k << 10) + tid;
        unsigned long long bal = __ballot((cmb[e] & 3u) == ST_A);  // e>=M stays U
        if (lane == 0) ballots[(k << 4) + wv] = bal;
    }
    __syncthreads();
    if (wv == 0) {
        unsigned int s = (unsigned int)__popcll(ballots[lane]);
        unsigned int v = s;
        for (int d = 1; d < 64; d <<= 1) {
            unsigned int u = __shfl_up(v, d, 64);
            if (lane >= d) v += u;
        }
        base64[lane] = v - s;
        if (lane == 63) sK = (int)v;
    }
    __syncthreads();
    #define KRANK(E) ((int)base64[(E) >> 6] +                                     \
                      __popcll(ballots[(E) >> 6] & ((1ull << ((E) & 63)) - 1ull)))

    // ---- P5+P6: rank-windowed passes (1 pass when sK <= LDSK: the norm) ----
    #define ROW_ARGMIN(CY, CX0, CX1, ME, BD, BE, BN)                              \
    {                                                                             \
        unsigned int wa = cellpack[(CY) * GRD + (CX0)];                           \
        unsigned int wb = cellpack[(CY) * GRD + (CX1)];                           \
        unsigned int f0 = wa >> 16, f1 = (wb >> 16) + (wb & 0xffffu);             \
        for (unsigned int f = f0; f < f1; ++f) {                                  \
            unsigned int wf = cmb[f];                                             \
            float2 q = sps[f];                                                    \
            float dx = __fsub_rn((ME).x, q.x), dy = __fsub_rn((ME).y, q.y);       \
            float d2 = __fadd_rn(__fmul_rn(dx, dx), __fmul_rn(dy, dy));           \
            int nf = (int)(wf >> 2);                                              \
            bool better = ((wf & 3u) == ST_A) &                                   \
                          ((d2 < BD) | ((d2 == BD) & (nf < BN)));                 \
            BD = better ? d2 : BD;                                                \
            BE = better ? (int)f : BE;                                            \
            BN = better ? nf : BN;                                                \
        }                                                                         \
    }
    const int npass = (sK + LDSK - 1) / LDSK;
    for (int pass = 0; pass < npass; ++pass) {
        const int rb = pass * LDSK;
        if (pass) {
            __syncthreads();
            for (int k = tid; k < LDSK; k += 1024) { ksx[k] = 0.f; ksy[k] = 0.f; kcn[k] = 0.f; }
        }
        __syncthreads();
        for (int e = tid; e < M; e += 1024) {
            unsigned int w = cmb[e];
            float2 me = sps[e];
            int be;
            if ((w & 3u) == ST_A) {
                be = e;                          // self: unique d2 = 0
            } else {
                int cx0 = max(0, (int)((me.x - RAD - bminx) * inv));
                int cx1 = min(GRD - 1, (int)((me.x + RAD - bminx) * inv));
                int cy0 = max(0, (int)((me.y - RAD - bminy) * inv));
                int cy1 = min(GRD - 1, (int)((me.y + RAD - bminy) * inv));
                float bd = 3e38f;
                be = -1;
                int bn = 1 << 30;
                ROW_ARGMIN(cy0, cx0, cx1, me, bd, be, bn);
                if (cy1 > cy0) ROW_ARGMIN(cy1, cx0, cx1, me, bd, be, bn);
                if (be < 0) continue;            // impossible when M > 0
            }
            int r = KRANK(be) - rb;
            if (r >= 0 && r < LDSK) {
                atomicAdd(&ksx[r], me.x);
                atomicAdd(&ksy[r], me.y);
                atomicAdd(&kcn[r], 1.0f);
            }
        }
        __syncthreads();
        for (int e = tid; e < M; e += 1024) {
            unsigned int w = cmb[e];
            if ((w & 3u) != ST_A) continue;
            int r = KRANK(e) - rb;
            if (r < 0 || r >= LDSK) continue;
            int n = (int)(w >> 2);
            float sx = ksx[r], sy = ksy[r], c = kcn[r];
            out[2 * (base + n)]     = sx / c;    // c >= 1 (self-assign)
            out[2 * (base + n) + 1] = sy / c;
            ok[n] = 1.0f;
        }
    }
}

// ---------------------------------------------------------------------------
extern "C" void kernel_launch(void* const* d_in, const int* in_sizes, int n_in,
                              void* d_out, int out_size, void* d_ws, size_t ws_size,
                              hipStream_t stream) {
    const float* seg   = (const float*)d_in[0];   // [B,C,H,W] f32
    const float* lidar = (const float*)d_in[1];   // [B,2,H,W] f32
    float* out = (float*)d_out;

    float* xs = (float*)d_ws;                     // 16384 f
    float* ys = xs + KBLK * KTHR;                 // 16384 f
    unsigned int* ns = (unsigned int*)(ys + KBLK * KTHR);   // 16384 u32
    unsigned int* counts = ns + KBLK * KTHR;      // KBLK*6 u32

    k_front<<<KBLK, KTHR, 0, stream>>>(seg, lidar, xs, ys, ns, counts, out);
    k_nms<<<NP, 1024, 0, stream>>>(xs, ys, ns, counts, out);
}